// Round 6
// baseline (70.876 us; speedup 1.0000x reference)
//
#include <hip/hip_runtime.h>

#define Wd 512
#define Hd 512
#define NIMG 48                      // 16 batch * 3 channels
#define RB 16                        // output rows per tile
#define LR (RB + 2)                  // staged rows incl. vertical halo
#define NT (NIMG * (Hd / RB))        // 1536 tiles
#define NBLK 256                     // 1 block per CU, persistent
#define TPB (NT / NBLK)              // 6 tiles per block
constexpr float INV_N = 1.0f / (float)((long long)NIMG * Hd * Wd);

// async global->LDS, 16 B per lane: HW writes lds_base + lane*16.
__device__ __forceinline__ void gload_lds16(const float* g, float* l) {
    __builtin_amdgcn_global_load_lds(
        (const __attribute__((address_space(1))) void*)g,
        (__attribute__((address_space(3))) void*)l, 16, 0, 0);
}

// Scharr on a 3x10 window; pixel j (0..7) uses cols j..j+2 of rows r0,r1,r2.
__device__ __forceinline__ float scharr_pix(const float r0[10], const float r1[10],
                                            const float r2[10], int j) {
    float tl = r0[j], tm = r0[j + 1], tr = r0[j + 2];
    float ml = r1[j],                  mr = r1[j + 2];
    float bl = r2[j], bm = r2[j + 1], br = r2[j + 2];
    float gx = 3.f * (tr - tl) + 10.f * (mr - ml) + 3.f * (br - bl);
    float gy = 3.f * (bl - tl) + 10.f * (bm - tm) + 3.f * (br - tr);
    return fabsf(gx) + fabsf(gy);
}

// Read cols [c0-1 .. c0+8] of one staged LDS row; halo via neighbor-lane shfl
// (wave spans the full 512-col row, lane edges == image edges -> zero).
__device__ __forceinline__ void lds_row(const float* __restrict__ row, int lane,
                                        float r[10]) {
    float4 b0 = *reinterpret_cast<const float4*>(row + lane * 8);
    float4 b1 = *reinterpret_cast<const float4*>(row + lane * 8 + 4);
    r[1] = b0.x; r[2] = b0.y; r[3] = b0.z; r[4] = b0.w;
    r[5] = b1.x; r[6] = b1.y; r[7] = b1.z; r[8] = b1.w;
    float lv = __shfl_up(b1.w, 1, 64);     // lane-1's col c0-1
    float rv = __shfl_down(b0.x, 1, 64);   // lane+1's col c0+8
    r[0] = (lane > 0)  ? lv : 0.f;
    r[9] = (lane < 63) ? rv : 0.f;
}

__global__ void __launch_bounds__(256)
scharr_loss_kernel(const float* __restrict__ x, const float* __restrict__ gt,
                   float* __restrict__ out) {
    __shared__ float lb[2][2][LR][Wd];   // [buf][img][row][col] = 144 KB
    __shared__ float ws[4];

    int wid  = threadIdx.x >> 6;
    int lane = threadIdx.x & 63;
    int is   = wid >> 1;                 // staging: which image this wave loads
    int half = wid & 1;                  // staging: which 256-float half-row
    const float* __restrict__ sb = (is ? gt : x);

    int t0 = blockIdx.x * TPB;           // 6 consecutive tiles per block

    // stage tile ti into LDS buffer `buf` (issue only; no wait here)
    auto stage = [&](int ti, int buf) {
        int img = ti >> 5;               // 32 tiles per image
        int h0  = (ti & 31) * RB;
        const float* __restrict__ ib = sb + (size_t)img * Hd * Wd;
        #pragma unroll
        for (int t = 0; t < LR; ++t) {
            int gh = h0 - 1 + t;
            float* dst = &lb[buf][is][t][half * 256];
            if ((unsigned)gh < (unsigned)Hd) {
                gload_lds16(ib + (size_t)gh * Wd + half * 256 + lane * 4, dst);
            } else {
                *reinterpret_cast<float4*>(dst + lane * 4) =
                    make_float4(0.f, 0.f, 0.f, 0.f);
            }
        }
    };

    float sum = 0.f;
    stage(t0, 0);
    __syncthreads();                     // drain tile 0

    #pragma unroll
    for (int k = 0; k < TPB; ++k) {
        if (k + 1 < TPB) stage(t0 + k + 1, (k + 1) & 1);   // prefetch next tile

        // --- compute tile k from buf k&1: wave owns 4 consecutive rows ---
        const int bf = k & 1;
        int r0 = wid * 4;
        float rx[3][10], rg[3][10];
        lds_row(&lb[bf][0][r0][0],     lane, rx[0]);
        lds_row(&lb[bf][0][r0 + 1][0], lane, rx[1]);
        lds_row(&lb[bf][1][r0][0],     lane, rg[0]);
        lds_row(&lb[bf][1][r0 + 1][0], lane, rg[1]);
        #pragma unroll
        for (int i = 0; i < 4; ++i) {
            const int c0 = i % 3, c1 = (i + 1) % 3, c2 = (i + 2) % 3;
            lds_row(&lb[bf][0][r0 + i + 2][0], lane, rx[c2]);
            lds_row(&lb[bf][1][r0 + i + 2][0], lane, rg[c2]);
            #pragma unroll
            for (int j = 0; j < 8; ++j) {
                float a = scharr_pix(rx[c0], rx[c1], rx[c2], j);
                float g = scharr_pix(rg[c0], rg[c1], rg[c2], j);
                sum += fabsf(a - g);
            }
        }

        // drains vmcnt(0) (next tile's loads landed) + protects buf reuse
        __syncthreads();
    }

    // wave reduce -> cross-wave LDS -> one atomic per block (256 total)
    #pragma unroll
    for (int off = 32; off > 0; off >>= 1)
        sum += __shfl_down(sum, off, 64);
    if (lane == 0) ws[wid] = sum;
    __syncthreads();
    if (threadIdx.x == 0)
        atomicAdd(out, (ws[0] + ws[1] + ws[2] + ws[3]) * INV_N);
}

extern "C" void kernel_launch(void* const* d_in, const int* in_sizes, int n_in,
                              void* d_out, int out_size, void* d_ws, size_t ws_size,
                              hipStream_t stream) {
    const float* x  = (const float*)d_in[0];
    const float* gt = (const float*)d_in[1];
    float* out      = (float*)d_out;

    // d_out is poisoned once before timing and never re-poisoned; zero each call.
    hipMemsetAsync(out, 0, sizeof(float), stream);

    scharr_loss_kernel<<<NBLK, 256, 0, stream>>>(x, gt, out);
}

// Round 7
// 37.194 us; speedup vs baseline: 1.9056x; 1.9056x over previous
//
#include <hip/hip_runtime.h>

#define Wd 512
#define Hd 512
#define NIMG 48                      // 16 batch * 3 channels
#define RB 16                        // output rows per tile
#define LR (RB + 2)                  // staged rows incl. vertical halo
#define NBLK (NIMG * (Hd / RB))      // 48*32 = 1536 blocks, one tile each
constexpr float INV_N = 1.0f / (float)((long long)NIMG * Hd * Wd);

// async global->LDS, 16 B per lane: HW writes lds_base + lane*16.
__device__ __forceinline__ void gload_lds16(const float* g, float* l) {
    __builtin_amdgcn_global_load_lds(
        (const __attribute__((address_space(1))) void*)g,
        (__attribute__((address_space(3))) void*)l, 16, 0, 0);
}

// Scharr on a 3x10 window; pixel j (0..7) uses cols j..j+2 of rows r0,r1,r2.
__device__ __forceinline__ float scharr_pix(const float r0[10], const float r1[10],
                                            const float r2[10], int j) {
    float tl = r0[j], tm = r0[j + 1], tr = r0[j + 2];
    float ml = r1[j],                  mr = r1[j + 2];
    float bl = r2[j], bm = r2[j + 1], br = r2[j + 2];
    float gx = 3.f * (tr - tl) + 10.f * (mr - ml) + 3.f * (br - bl);
    float gy = 3.f * (bl - tl) + 10.f * (bm - tm) + 3.f * (br - tr);
    return fabsf(gx) + fabsf(gy);
}

// Read cols [c0-1 .. c0+8] of one staged LDS row; halo via neighbor-lane shfl
// (wave spans the full 512-col row, lane edges == image edges -> zero).
__device__ __forceinline__ void lds_row(const float* __restrict__ row, int lane,
                                        float r[10]) {
    float4 b0 = *reinterpret_cast<const float4*>(row + lane * 8);
    float4 b1 = *reinterpret_cast<const float4*>(row + lane * 8 + 4);
    r[1] = b0.x; r[2] = b0.y; r[3] = b0.z; r[4] = b0.w;
    r[5] = b1.x; r[6] = b1.y; r[7] = b1.z; r[8] = b1.w;
    float lv = __shfl_up(b1.w, 1, 64);     // lane-1's col c0-1
    float rv = __shfl_down(b0.x, 1, 64);   // lane+1's col c0+8
    r[0] = (lane > 0)  ? lv : 0.f;
    r[9] = (lane < 63) ? rv : 0.f;
}

__global__ void __launch_bounds__(512)
scharr_loss_kernel(const float* __restrict__ x, const float* __restrict__ gt,
                   float* __restrict__ out) {
    __shared__ float lb[2][LR][Wd];      // 72 KB -> 2 blocks/CU, 16 waves/CU
    __shared__ float ws[8];

    int wid  = threadIdx.x >> 6;         // 0..7
    int lane = threadIdx.x & 63;

    // Bijective XCD swizzle (NBLK % 8 == 0): consecutive tiles of one image
    // land on the same XCD -> block-boundary halo rows are L2 hits.
    int b   = blockIdx.x;
    int swz = (b & 7) * (NBLK / 8) + (b >> 3);
    int img = swz >> 5;                  // 32 tiles per image
    int h0  = (swz & 31) * RB;

    const float* __restrict__ xb = x  + (size_t)img * Hd * Wd;
    const float* __restrict__ gb = gt + (size_t)img * Hd * Wd;

    // --- stage: 72 chunks of 1 KB (2 img x 18 rows x 2 halves), 9 per wave ---
    #pragma unroll
    for (int t = 0; t < 9; ++t) {
        int c    = wid + t * 8;          // 0..71, full coverage
        int im   = (c >= 36) ? 1 : 0;
        int cc   = c - im * 36;
        int row  = cc >> 1;
        int half = cc & 1;
        int gh   = h0 - 1 + row;
        const float* __restrict__ sb = im ? gb : xb;
        float* dst = &lb[im][row][half * 256];
        if ((unsigned)gh < (unsigned)Hd) {
            gload_lds16(sb + (size_t)gh * Wd + half * 256 + lane * 4, dst);
        } else {
            *reinterpret_cast<float4*>(dst + lane * 4) =
                make_float4(0.f, 0.f, 0.f, 0.f);
        }
    }
    __syncthreads();                     // single vmcnt(0) drain per block

    // --- compute: wave w owns local output rows 2w, 2w+1 ---
    int lr = wid * 2;                    // lb rows lr..lr+3 feed these outputs
    float rx[3][10], rg[3][10];
    lds_row(&lb[0][lr][0],     lane, rx[0]);
    lds_row(&lb[0][lr + 1][0], lane, rx[1]);
    lds_row(&lb[1][lr][0],     lane, rg[0]);
    lds_row(&lb[1][lr + 1][0], lane, rg[1]);

    float sum = 0.f;
    #pragma unroll
    for (int i = 0; i < 2; ++i) {
        const int c0 = i % 3, c1 = (i + 1) % 3, c2 = (i + 2) % 3;
        lds_row(&lb[0][lr + i + 2][0], lane, rx[c2]);
        lds_row(&lb[1][lr + i + 2][0], lane, rg[c2]);
        #pragma unroll
        for (int j = 0; j < 8; ++j) {
            float a = scharr_pix(rx[c0], rx[c1], rx[c2], j);
            float g = scharr_pix(rg[c0], rg[c1], rg[c2], j);
            sum += fabsf(a - g);
        }
    }

    // wave reduce -> cross-wave LDS -> one atomic per block (1536 total)
    #pragma unroll
    for (int off = 32; off > 0; off >>= 1)
        sum += __shfl_down(sum, off, 64);
    if (lane == 0) ws[wid] = sum;
    __syncthreads();
    if (threadIdx.x == 0) {
        float s = ws[0] + ws[1] + ws[2] + ws[3]
                + ws[4] + ws[5] + ws[6] + ws[7];
        atomicAdd(out, s * INV_N);
    }
}

extern "C" void kernel_launch(void* const* d_in, const int* in_sizes, int n_in,
                              void* d_out, int out_size, void* d_ws, size_t ws_size,
                              hipStream_t stream) {
    const float* x  = (const float*)d_in[0];
    const float* gt = (const float*)d_in[1];
    float* out      = (float*)d_out;

    // d_out is poisoned once before timing and never re-poisoned; zero each call.
    hipMemsetAsync(out, 0, sizeof(float), stream);

    scharr_loss_kernel<<<NBLK, 512, 0, stream>>>(x, gt, out);
}

// Round 8
// 25.191 us; speedup vs baseline: 2.8135x; 1.4765x over previous
//
#include <hip/hip_runtime.h>

#define Wd 512
#define Hd 512
#define NIMG 48                      // 16 batch * 3 channels
#define RB 8                         // output rows per tile
#define LR (RB + 2)                  // staged rows incl. vertical halo
#define NBLK (NIMG * (Hd / RB))      // 48*64 = 3072 blocks, one tile each
constexpr float INV_N = 1.0f / (float)((long long)NIMG * Hd * Wd);

// async global->LDS, 16 B per lane: HW writes lds_base + lane*16.
__device__ __forceinline__ void gload_lds16(const float* g, float* l) {
    __builtin_amdgcn_global_load_lds(
        (const __attribute__((address_space(1))) void*)g,
        (__attribute__((address_space(3))) void*)l, 16, 0, 0);
}

// Scharr on a 3x10 window; pixel j (0..7) uses cols j..j+2 of rows r0,r1,r2.
__device__ __forceinline__ float scharr_pix(const float r0[10], const float r1[10],
                                            const float r2[10], int j) {
    float tl = r0[j], tm = r0[j + 1], tr = r0[j + 2];
    float ml = r1[j],                  mr = r1[j + 2];
    float bl = r2[j], bm = r2[j + 1], br = r2[j + 2];
    float gx = 3.f * (tr - tl) + 10.f * (mr - ml) + 3.f * (br - bl);
    float gy = 3.f * (bl - tl) + 10.f * (bm - tm) + 3.f * (br - tr);
    return fabsf(gx) + fabsf(gy);
}

// Read cols [c0-1 .. c0+8] of one staged LDS row; halo via neighbor-lane shfl
// (wave spans the full 512-col row, lane edges == image edges -> zero).
__device__ __forceinline__ void lds_row(const float* __restrict__ row, int lane,
                                        float r[10]) {
    float4 b0 = *reinterpret_cast<const float4*>(row + lane * 8);
    float4 b1 = *reinterpret_cast<const float4*>(row + lane * 8 + 4);
    r[1] = b0.x; r[2] = b0.y; r[3] = b0.z; r[4] = b0.w;
    r[5] = b1.x; r[6] = b1.y; r[7] = b1.z; r[8] = b1.w;
    float lv = __shfl_up(b1.w, 1, 64);     // lane-1's col c0-1
    float rv = __shfl_down(b0.x, 1, 64);   // lane+1's col c0+8
    r[0] = (lane > 0)  ? lv : 0.f;
    r[9] = (lane < 63) ? rv : 0.f;
}

__global__ void __launch_bounds__(256, 4)
scharr_loss_kernel(const float* __restrict__ x, const float* __restrict__ gt,
                   float* __restrict__ partials) {
    __shared__ float lb[2][LR][Wd];      // exactly 40 KB -> 4 blocks/CU

    int wid  = threadIdx.x >> 6;         // 0..3
    int lane = threadIdx.x & 63;

    // Bijective XCD swizzle (NBLK % 8 == 0): consecutive tiles of one image
    // land on the same XCD -> block-boundary halo rows are L2 hits.
    int b   = blockIdx.x;
    int swz = (b & 7) * (NBLK / 8) + (b >> 3);
    int img = swz >> 6;                  // 64 tiles per image
    int h0  = (swz & 63) * RB;

    const float* __restrict__ xb = x  + (size_t)img * Hd * Wd;
    const float* __restrict__ gb = gt + (size_t)img * Hd * Wd;

    // --- stage: 40 chunks of 1 KB (2 img x 10 rows x 2 halves), 10 per wave ---
    #pragma unroll
    for (int t = 0; t < 10; ++t) {
        int c    = wid + t * 4;          // 0..39, wave-uniform
        int im   = (c >= 20) ? 1 : 0;
        int cc   = c - im * 20;
        int row  = cc >> 1;
        int half = cc & 1;
        int gh   = h0 - 1 + row;
        const float* __restrict__ sb = im ? gb : xb;
        float* dst = &lb[im][row][half * 256];
        if ((unsigned)gh < (unsigned)Hd) {
            gload_lds16(sb + (size_t)gh * Wd + half * 256 + lane * 4, dst);
        } else {
            *reinterpret_cast<float4*>(dst + lane * 4) =
                make_float4(0.f, 0.f, 0.f, 0.f);
        }
    }
    __syncthreads();                     // single vmcnt(0) drain per block

    // --- compute: wave w owns local output rows 2w, 2w+1 ---
    int lr = wid * 2;
    float rx[3][10], rg[3][10];
    lds_row(&lb[0][lr][0],     lane, rx[0]);
    lds_row(&lb[0][lr + 1][0], lane, rx[1]);
    lds_row(&lb[1][lr][0],     lane, rg[0]);
    lds_row(&lb[1][lr + 1][0], lane, rg[1]);

    float sum = 0.f;
    #pragma unroll
    for (int i = 0; i < 2; ++i) {
        const int c0 = i % 3, c1 = (i + 1) % 3, c2 = (i + 2) % 3;
        lds_row(&lb[0][lr + i + 2][0], lane, rx[c2]);
        lds_row(&lb[1][lr + i + 2][0], lane, rg[c2]);
        #pragma unroll
        for (int j = 0; j < 8; ++j) {
            float a = scharr_pix(rx[c0], rx[c1], rx[c2], j);
            float g = scharr_pix(rg[c0], rg[c1], rg[c2], j);
            sum += fabsf(a - g);
        }
    }

    // wave reduce; cross-wave partials reuse lb (keeps LDS at exactly 40 KB)
    #pragma unroll
    for (int off = 32; off > 0; off >>= 1)
        sum += __shfl_down(sum, off, 64);
    __syncthreads();                     // all waves done reading lb
    if (lane == 0) lb[0][0][wid] = sum;
    __syncthreads();
    if (threadIdx.x == 0)
        partials[blockIdx.x] = lb[0][0][0] + lb[0][0][1]
                             + lb[0][0][2] + lb[0][0][3];
}

__global__ void __launch_bounds__(256)
reduce_partials_kernel(const float* __restrict__ partials, float* __restrict__ out) {
    const float4* p4 = reinterpret_cast<const float4*>(partials);
    float s = 0.f;
    #pragma unroll
    for (int k = 0; k < NBLK / 4 / 256; ++k) {    // 3 float4s per thread
        float4 v = p4[k * 256 + threadIdx.x];
        s += v.x + v.y + v.z + v.w;
    }
    #pragma unroll
    for (int off = 32; off > 0; off >>= 1)
        s += __shfl_down(s, off, 64);
    __shared__ float ws[4];
    int lane = threadIdx.x & 63;
    int wid  = threadIdx.x >> 6;
    if (lane == 0) ws[wid] = s;
    __syncthreads();
    if (threadIdx.x == 0)
        out[0] = (ws[0] + ws[1] + ws[2] + ws[3]) * INV_N;
}

extern "C" void kernel_launch(void* const* d_in, const int* in_sizes, int n_in,
                              void* d_out, int out_size, void* d_ws, size_t ws_size,
                              hipStream_t stream) {
    const float* x  = (const float*)d_in[0];
    const float* gt = (const float*)d_in[1];
    float* out      = (float*)d_out;
    float* partials = (float*)d_ws;      // NBLK floats = 12 KB

    scharr_loss_kernel<<<NBLK, 256, 0, stream>>>(x, gt, partials);
    reduce_partials_kernel<<<1, 256, 0, stream>>>(partials, out);
}